// Round 26
// baseline (1039.081 us; speedup 1.0000x reference)
//
#include <hip/hip_runtime.h>
#include <math.h>

// ---------------- constants ----------------
constexpr int ROWS_PER_B = 12 * 1024;    // rows (b,t,n) per batch element

// ---------------- graph workspace (float offsets, < 524288) ----------------
constexpr size_t F_N1 = 0;              // 1024*40
constexpr size_t F_N2 = 40960;
constexpr size_t F_ANVAL = 81920;       // 1024*11
constexpr size_t F_ROWVAL = 93184;      // 1024*10
constexpr size_t F_COLSUM = 103424;     // 1024
constexpr size_t F_INVCS = 104448;      // 1024
constexpr size_t F_ATVAL = 105472;      // 10240
constexpr size_t I_ANIDX = 115712;      // ints stored in float slots
constexpr size_t I_ROWIDX = 126976;
constexpr size_t I_COLCNT = 137216;
constexpr size_t I_COLOFF = 138240;     // 1025
constexpr size_t I_COLFILL = 139265;
constexpr size_t I_ATIDX = 140289;      // ends 150529
constexpr size_t F_W1P = 151552;        // packed bf16 Wtf1: 32768 floats
constexpr size_t F_W2P = 184320;        // packed bf16 Wtf2: ends 217088
constexpr size_t F_WFCP = 217088;       // packed bf16 Wfc1: ends 339968
constexpr size_t F_WEC1P = 339968;      // packed bf16 Wec1
constexpr size_t F_WEC2P = 342016;      // packed bf16 Wec2 -> ends 343040
constexpr size_t F_WMWP = 343040;       // packed bf16 mix weights -> ends 349184
constexpr size_t GRAPH_FLOATS = 524288;

// per-chunk float-unit counts (per batch element) — bf16 storage
constexpr size_t PB_GATED = (size_t)ROWS_PER_B * 128 / 2;   // 786432
constexpr size_t PB_HD = (size_t)ROWS_PER_B * 64 / 2;       // 393216
constexpr size_t PB_X = (size_t)32 * 1024 * 64 / 2;         // 1048576 per xp slab
constexpr size_t PB_MIX = (size_t)32 * 1024 * 256 / 2;      // 4194304
// x-chain is double-buffered over xp (xs,h1,h2,h1b,h2b each x2); apk aliases mix
constexpr size_t PB_TOTAL = PB_GATED + PB_HD + 10 * PB_X + PB_MIX; // 15859712

typedef __attribute__((ext_vector_type(8))) short bf16x8;
typedef __attribute__((ext_vector_type(4))) float f32x4;
typedef __attribute__((ext_vector_type(2))) float f32x2;

__device__ __forceinline__ unsigned short f2bf(float f) {
    unsigned u = __float_as_uint(f);
    unsigned r = (u + 0x7fffu + ((u >> 16) & 1u)) >> 16;   // RNE
    return (unsigned short)r;
}
__device__ __forceinline__ float bf2f(unsigned short h) {
    return __uint_as_float((unsigned)h << 16);
}
__device__ __forceinline__ void unpack8(uint4 raw, float* f) {
    f[0] = bf2f((unsigned short)(raw.x & 0xffff)); f[1] = bf2f((unsigned short)(raw.x >> 16));
    f[2] = bf2f((unsigned short)(raw.y & 0xffff)); f[3] = bf2f((unsigned short)(raw.y >> 16));
    f[4] = bf2f((unsigned short)(raw.z & 0xffff)); f[5] = bf2f((unsigned short)(raw.z >> 16));
    f[6] = bf2f((unsigned short)(raw.w & 0xffff)); f[7] = bf2f((unsigned short)(raw.w >> 16));
}
// packed-pair unpack: same f32 values/order as unpack8, 1 VALU op per element
__device__ __forceinline__ void unpack8p(uint4 raw, f32x2* f) {
    f[0].x = __uint_as_float(raw.x << 16); f[0].y = __uint_as_float(raw.x & 0xffff0000u);
    f[1].x = __uint_as_float(raw.y << 16); f[1].y = __uint_as_float(raw.y & 0xffff0000u);
    f[2].x = __uint_as_float(raw.z << 16); f[2].y = __uint_as_float(raw.z & 0xffff0000u);
    f[3].x = __uint_as_float(raw.w << 16); f[3].y = __uint_as_float(raw.w & 0xffff0000u);
}
__device__ __forceinline__ uint4 pack8(const float* f) {
    uint4 r;
    r.x = f2bf(f[0]) | ((unsigned)f2bf(f[1]) << 16);
    r.y = f2bf(f[2]) | ((unsigned)f2bf(f[3]) << 16);
    r.z = f2bf(f[4]) | ((unsigned)f2bf(f[5]) << 16);
    r.w = f2bf(f[6]) | ((unsigned)f2bf(f[7]) << 16);
    return r;
}
__device__ __forceinline__ uint4 pack8p(const f32x2* f) {
    uint4 r;
    r.x = f2bf(f[0].x) | ((unsigned)f2bf(f[0].y) << 16);
    r.y = f2bf(f[1].x) | ((unsigned)f2bf(f[1].y) << 16);
    r.z = f2bf(f[2].x) | ((unsigned)f2bf(f[2].y) << 16);
    r.w = f2bf(f[3].x) | ((unsigned)f2bf(f[3].y) << 16);
    return r;
}
__device__ __forceinline__ bf16x8 relu8(bf16x8 v) {
#pragma unroll
    for (int j = 0; j < 8; j++) {
        unsigned short u = (unsigned short)v[j];
        v[j] = (short)((u >> 15) ? 0 : u);
    }
    return v;
}

// ---------------- graph kernels ----------------

__global__ void k_init(int* cnt, int* fill, float* csum) {
    int t = blockIdx.x * 256 + threadIdx.x;
    if (t < 1024) { cnt[t] = 0; fill[t] = 0; csum[t] = 0.f; }
}

__global__ void k_embed(const float* e1, const float* e2, const float* w1, const float* b1,
                        const float* w2, const float* b2, float* n1, float* n2) {
    int idx = blockIdx.x * 256 + threadIdx.x;   // < 81920
    if (idx >= 81920) return;
    int m = idx / 40960, rem = idx - m * 40960;
    int i = rem / 40, j = rem - i * 40;
    const float* e = m ? e2 : e1;
    const float* w = m ? w2 : w1;
    const float* bv = m ? b2 : b1;
    float a = bv[j];
    for (int k = 0; k < 40; k++) a += e[i * 40 + k] * w[k * 40 + j];
    (m ? n2 : n1)[i * 40 + j] = tanhf(3.0f * a);
}

__global__ __launch_bounds__(256) void k_adj(const float* n1, const float* n2,
        float* aN_val, int* aN_idx, float* row_val, int* row_idx,
        int* col_cnt, float* col_sum) {
    __shared__ float arow[1024];
    __shared__ float n1v[40], n2v[40];
    __shared__ float rv[256];
    __shared__ int ri[256];
    __shared__ float topv[10];
    __shared__ int topi[10];
    int v = blockIdx.x, t = threadIdx.x;
    if (t < 40) { n1v[t] = n1[v * 40 + t]; n2v[t] = n2[v * 40 + t]; }
    __syncthreads();
    for (int j = t; j < 1024; j += 256) {
        float d1 = 0.f, d2 = 0.f;
        for (int k = 0; k < 40; k++) {
            d1 += n1v[k] * n2[j * 40 + k];
            d2 += n2v[k] * n1[j * 40 + k];
        }
        float a = tanhf(3.0f * (d1 - d2));
        arow[j] = a > 0.f ? a : 0.f;
    }
    __syncthreads();
    for (int r = 0; r < 10; r++) {
        float bv = -1.f; int bi = 1 << 30;
        for (int j = t; j < 1024; j += 256) {
            float x = arow[j];
            if (x > bv || (x == bv && j < bi)) { bv = x; bi = j; }
        }
        rv[t] = bv; ri[t] = bi;
        __syncthreads();
        for (int s = 128; s > 0; s >>= 1) {
            if (t < s) {
                float ov = rv[t + s]; int oi = ri[t + s];
                if (ov > rv[t] || (ov == rv[t] && oi < ri[t])) { rv[t] = ov; ri[t] = oi; }
            }
            __syncthreads();
        }
        if (t == 0) { topv[r] = rv[0]; topi[r] = ri[0]; arow[ri[0]] = -1.f; }
        __syncthreads();
    }
    if (t == 0) {
        float s = 1.f;
        for (int r = 0; r < 10; r++) s += topv[r];
        float inv = 1.f / s;
        for (int r = 0; r < 10; r++) {
            aN_idx[v * 11 + r] = topi[r];
            aN_val[v * 11 + r] = topv[r] * inv;
            row_idx[v * 10 + r] = topi[r];
            row_val[v * 10 + r] = topv[r];
            atomicAdd(&col_cnt[topi[r]], 1);
            atomicAdd(&col_sum[topi[r]], topv[r]);
        }
        aN_idx[v * 11 + 10] = v;
        aN_val[v * 11 + 10] = inv;
    }
}

__global__ __launch_bounds__(1024) void k_scan(const int* cnt, int* off,
                                               const float* csum, float* inv) {
    __shared__ int tmp[1024];
    int t = threadIdx.x;
    tmp[t] = cnt[t];
    __syncthreads();
    for (int s = 1; s < 1024; s <<= 1) {
        int v = 0;
        if (t >= s) v = tmp[t - s];
        __syncthreads();
        tmp[t] += v;
        __syncthreads();
    }
    off[t + 1] = tmp[t];
    if (t == 0) off[0] = 0;
    inv[t] = 1.0f / (csum[t] + 1.0f);
}

__global__ void k_scatter(const int* row_idx, const float* row_val, const int* off,
                          int* fill, int* aT_idx, float* aT_val) {
    int e = blockIdx.x * 256 + threadIdx.x;
    if (e >= 10240) return;
    int v = e / 10;
    int j = row_idx[e];
    int pos = off[j] + atomicAdd(&fill[j], 1);
    aT_idx[pos] = v;
    aT_val[pos] = row_val[e];
}

// pack 256x256 f32 weight into MFMA B-fragment order
__global__ void k_packw(const float* W, unsigned short* out) {
    int id = blockIdx.x * 256 + threadIdx.x;    // 8192 total
    if (id >= 8192) return;
    int lane = id & 63, rest = id >> 6;
    int nb = rest & 15, kb = rest >> 4;
    int krow = kb * 32 + (lane >> 4) * 8;
    int col = nb * 16 + (lane & 15);
    unsigned short v[8];
#pragma unroll
    for (int j = 0; j < 8; j++) v[j] = f2bf(W[(size_t)(krow + j) * 256 + col]);
#pragma unroll
    for (int j = 0; j < 8; j++) out[(size_t)id * 8 + j] = v[j];
}

// pack 472x512 Wfc1 into B-fragment order, K padded to 480
__global__ void k_packfc(const float* W, unsigned short* out) {
    int id = blockIdx.x * 256 + threadIdx.x;    // 30720 total
    if (id >= 30720) return;
    int lane = id & 63, rest = id >> 6;
    int nb = rest & 31, kb = rest >> 5;         // kb < 15
    int k0 = kb * 32 + (lane >> 4) * 8;
    int col = nb * 16 + (lane & 15);
    unsigned short v[8];
#pragma unroll
    for (int j = 0; j < 8; j++) {
        int k = k0 + j;
        v[j] = (k < 472) ? f2bf(W[(size_t)k * 512 + col]) : (unsigned short)0;
    }
#pragma unroll
    for (int j = 0; j < 8; j++) out[(size_t)id * 8 + j] = v[j];
}

// pack Wec1 (128x32) and Wec2 (12x128, pad 16) into A-frag order
__global__ void k_packec(const float* W1, const float* W2,
                         unsigned short* o1, unsigned short* o2) {
    int id = blockIdx.x * 256 + threadIdx.x;    // 768 total
    if (id < 512) {
        int mt = id >> 6, lane = id & 63;
        int o = mt * 16 + (lane & 15);
        int c0 = (lane >> 4) * 8;
#pragma unroll
        for (int j = 0; j < 8; j++)
            o1[(size_t)id * 8 + j] = f2bf(W1[o * 32 + c0 + j]);
    } else if (id < 768) {
        int id2 = id - 512;
        int kb = id2 >> 6, lane = id2 & 63;
        int p = lane & 15;
        int k0 = kb * 32 + (lane >> 4) * 8;
#pragma unroll
        for (int j = 0; j < 8; j++)
            o2[(size_t)id2 * 8 + j] = (p < 12) ? f2bf(W2[p * 128 + k0 + j])
                                               : (unsigned short)0;
    }
}

// pack mix weights [64 rows][192 K] into A-frag order (24 frags)
__global__ void k_packmw(const float* mw1, const float* mw2, unsigned short* out) {
    int id = blockIdx.x * 256 + threadIdx.x;    // 1536 total
    if (id >= 1536) return;
    int f = id >> 6, lane = id & 63;
    int kb = f >> 2, rt = f & 3;
    int row = rt * 16 + (lane & 15);
    int ph = (kb >= 3) ? 1 : 0;
    int kloc = (kb - ph * 3) * 32 + (lane >> 4) * 8;
    const float* mw = ph ? mw2 : mw1;
#pragma unroll
    for (int j = 0; j < 8; j++)
        out[(size_t)id * 8 + j] = f2bf(mw[row * 96 + kloc + j]);
}

// ---------------- per-chunk kernels ----------------

// gate MLP + embed; 16 rows/block (weights staged once, float4); grid = CB*768
__global__ __launch_bounds__(256) void k_gate(const float* hist, const float* nodeu,
        const float* tide, const float* diwe,
        const float* Wg1, const float* bg1, const float* Wg2, const float* bg2,
        const float* Wemb, const float* bemb, unsigned short* gated, unsigned short* hd_emb) {
    __shared__ float w1[4096], w2[4096];
    __shared__ float gin[4][64], hid[4][64];
    __shared__ float sb1[64], sb2[64], we[128], be[64];
    int t = threadIdx.x;
    for (int i = t; i < 1024; i += 256) {
        ((float4*)w1)[i] = ((const float4*)Wg1)[i];
        ((float4*)w2)[i] = ((const float4*)Wg2)[i];
    }
    if (t < 64) { sb1[t] = bg1[t]; sb2[t] = bg2[t]; be[t] = bemb[t]; }
    if (t < 128) we[t] = Wemb[t];
    int r = t >> 6, lane = t & 63;
    __syncthreads();
#pragma unroll
    for (int it = 0; it < 4; it++) {
        int row = blockIdx.x * 16 + it * 4 + r;
        int n = row & 1023;
        const float* hrow = hist + (size_t)row * 4;
        float f0 = hrow[0], f1 = hrow[1];
        int tid_i = (int)(hrow[2] * 288.0f);
        int diw_i = (int)hrow[3];
        float g;
        if (lane < 40) g = nodeu[n * 40 + lane];
        else if (lane < 52) g = tide[tid_i * 12 + lane - 40];
        else g = diwe[diw_i * 12 + lane - 52];
        gin[r][lane] = g;
        __syncthreads();
        float acc = sb1[lane];
        for (int k = 0; k < 64; k++) acc += gin[r][k] * w1[k * 64 + lane];
        hid[r][lane] = acc > 0.f ? acc : 0.f;
        __syncthreads();
        acc = sb2[lane];
        for (int k = 0; k < 64; k++) acc += hid[r][k] * w2[k * 64 + lane];
        float gate = 1.f / (1.f + expf(-acc));
        float hd = f0 * we[lane] + f1 * we[64 + lane] + be[lane];
        float x1 = gate * hd;
        gated[(size_t)row * 128 + lane] = f2bf(x1);
        gated[(size_t)row * 128 + 64 + lane] = f2bf(hd - x1);
        hd_emb[(size_t)row * 64 + lane] = f2bf(hd);
        __syncthreads();
    }
}

// xs = relu(sum_t gated*Wsc + bsc), both xp halves; grid = dim3(CB*256, 2)
__global__ __launch_bounds__(256) void k_wsc(const unsigned short* gated, const float* Wsc,
                                             const float* bsc, unsigned short* xs,
                                             size_t xstride) {
    __shared__ float w[384];
    __shared__ float sb[32];
    int t = threadIdx.x;
    if (t < 384) w[t] = Wsc[t];
    if (t < 32) sb[t] = bsc[t];
    __syncthreads();
    int xoff = blockIdx.y * 64;
    unsigned short* out = xs + (size_t)blockIdx.y * xstride;
    int idx = blockIdx.x * 256 + t;
    int h = idx & 63, n = (idx >> 6) & 1023, b = idx >> 16;
    float xv[12];
#pragma unroll
    for (int tt = 0; tt < 12; tt++)
        xv[tt] = bf2f(gated[(size_t)((b * 12 + tt) * 1024 + n) * 128 + xoff + h]);
#pragma unroll
    for (int o = 0; o < 32; o++) {
        float a = sb[o];
#pragma unroll
        for (int tt = 0; tt < 12; tt++) a += xv[tt] * w[o * 12 + tt];
        out[(size_t)((b * 32 + o) * 1024 + n) * 64 + h] = f2bf(a > 0.f ? a : 0.f);
    }
}

// fused dual spmm, split by PATH: blockIdx.y = xp*2 + path.
// path0: out1 = .05x + .95*aN@hin1 (11 gathers); path1: out2 = .05x + .95*aTN@hin2
// (16 prefetched + tail). Packed-f32 (v_pk_fma_f32) inner math — same element
// order/values as the scalar version. bf16 in/out; XCD-swizzled.
// grid = dim3(CB*1024, 4)
__global__ __launch_bounds__(256) void k_spmm2(unsigned short* out1, unsigned short* out2,
        const unsigned short* x, const unsigned short* hin1, const unsigned short* hin2,
        const int* aN_idx, const float* aN_val,
        const int* aT_idx, const float* aT_val,
        const int* off, const float* inv_cs, size_t xstride) {
    int xp = blockIdx.y >> 1, path = blockIdx.y & 1;
    size_t xoffs = (size_t)xp * xstride;
    x += xoffs;
    int nper = gridDim.x >> 3;
    int bid = (blockIdx.x & 7) * nper + (blockIdx.x >> 3);   // same-bc blocks -> same XCD
    int t = threadIdx.x;
    int l8 = t & 7, r = t >> 3;             // 32 rows x 8 16B-lanes
    int g = bid * 32 + r;
    int v = g & 1023, bc = g >> 10;
    size_t rowoff = (size_t)bc * 65536;
    f32x2 hv[4], s[4], o[4], xv[4];
    if (path == 0) {
        // ---- aN path (11 fixed edges, independent gathers) ----
        const unsigned short* base1 = hin1 + xoffs + rowoff;
#pragma unroll
        for (int j = 0; j < 4; j++) { s[j].x = 0.f; s[j].y = 0.f; }
#pragma unroll
        for (int e = 0; e < 11; e++) {
            int w = aN_idx[v * 11 + e];
            float a = aN_val[v * 11 + e];
            f32x2 a2; a2.x = a; a2.y = a;
            uint4 raw = *(const uint4*)(base1 + (size_t)w * 64 + l8 * 8);
            unpack8p(raw, hv);
#pragma unroll
            for (int j = 0; j < 4; j++) s[j] = __builtin_elementwise_fma(a2, hv[j], s[j]);
        }
        uint4 xr = *(const uint4*)(x + (size_t)g * 64 + l8 * 8);
        unpack8p(xr, xv);
        f32x2 c05; c05.x = 0.05f; c05.y = 0.05f;
        f32x2 c95; c95.x = 0.95f; c95.y = 0.95f;
#pragma unroll
        for (int j = 0; j < 4; j++)
            o[j] = __builtin_elementwise_fma(c95, s[j], c05 * xv[j]);
        *(uint4*)(out1 + xoffs + (size_t)g * 64 + l8 * 8) = pack8p(o);
    } else {
        // ---- aTN path: 16 prefetched independent gathers (ascending e) + tail ----
        int e0 = off[v], e1 = off[v + 1];
        int ti[16]; float tv[16];
#pragma unroll
        for (int k = 0; k < 16; k++) {
            int e = e0 + k;
            int es = (e < e1) ? e : e0;          // clamp: always a valid address
            ti[k] = aT_idx[es];
            tv[k] = (e < e1) ? aT_val[es] : 0.f; // padding weight 0 -> no-op accumulate
        }
        const unsigned short* base2 = hin2 + xoffs + rowoff;
        uint4 raw = *(const uint4*)(base2 + (size_t)v * 64 + l8 * 8);
        unpack8p(raw, s);
#pragma unroll
        for (int k = 0; k < 16; k++) {
            f32x2 a2; a2.x = tv[k]; a2.y = tv[k];
            uint4 rw = *(const uint4*)(base2 + (size_t)ti[k] * 64 + l8 * 8);
            unpack8p(rw, hv);
#pragma unroll
            for (int j = 0; j < 4; j++) s[j] = __builtin_elementwise_fma(a2, hv[j], s[j]);
        }
        for (int e = e0 + 16; e < e1; e++) {   // rare tail (degree > 16)
            float a = aT_val[e];
            f32x2 a2; a2.x = a; a2.y = a;
            uint4 rw = *(const uint4*)(base2 + (size_t)aT_idx[e] * 64 + l8 * 8);
            unpack8p(rw, hv);
#pragma unroll
            for (int j = 0; j < 4; j++) s[j] = __builtin_elementwise_fma(a2, hv[j], s[j]);
        }
        float ic = inv_cs[v];
        f32x2 ic2; ic2.x = ic; ic2.y = ic;
        uint4 xr = *(const uint4*)(x + (size_t)g * 64 + l8 * 8);
        unpack8p(xr, xv);
        f32x2 c05; c05.x = 0.05f; c05.y = 0.05f;
        f32x2 c95; c95.x = 0.95f; c95.y = 0.95f;
#pragma unroll
        for (int j = 0; j < 4; j++)
            o[j] = __builtin_elementwise_fma(c95, ic2 * s[j], c05 * xv[j]);
        *(uint4*)(out2 + xoffs + (size_t)g * 64 + l8 * 8) = pack8p(o);
    }
}

// mix projection via bf16 MFMA, both xp halves: block = (b,n); grid = dim3(CB*1024, 2)
__global__ __launch_bounds__(256) void k_proj(const unsigned short* xs,
        const unsigned short* h1, const unsigned short* h2,
        const unsigned short* h1b, const unsigned short* h2b,
        const unsigned short* mwp, const float* m1b, const float* m2b,
        unsigned short* mix, size_t xstride) {
    __shared__ unsigned short Bf[24 * 64 * 8];   // 24 shared B-frags, frag layout, 24 KB
    int xp = blockIdx.y;
    size_t xoffs = (size_t)xp * xstride;
    xs += xoffs; h1 += xoffs; h2 += xoffs; h1b += xoffs; h2b += xoffs;
    int t = threadIdx.x;
    int wave = t >> 6, l = t & 63;
    int lr = l & 15, lg = l >> 4;
    int b = blockIdx.x >> 10, n = blockIdx.x & 1023;
    // ---- cooperative B-frag gather: 6 frags per wave ----
#pragma unroll
    for (int i = 0; i < 6; i++) {
        int f = wave * 6 + i;
        int kb = f >> 2, nt = f & 3;
        int ph = (kb >= 3) ? 1 : 0;
        int q = kb - ph * 3;
        const unsigned short* Hq = (q == 0) ? xs : (q == 1 ? (ph ? h1b : h1)
                                                           : (ph ? h2b : h2));
        const unsigned short* src = Hq + ((size_t)(b * 32 + lg * 8) * 1024 + n) * 64
                                       + nt * 16 + lr;
        bf16x8 v;
#pragma unroll
        for (int j = 0; j < 8; j++)
            v[j] = (short)src[(size_t)j * 65536];
        *(bf16x8*)(Bf + ((size_t)f * 64 + l) * 8) = v;
    }
    __syncthreads();
    // ---- wave = row-tile; 4 col-tiles; K = 6 blocks of 32 ----
    f32x4 acc[4];
#pragma unroll
    for (int nt = 0; nt < 4; nt++) {
        f32x4 c;
#pragma unroll
        for (int r = 0; r < 4; r++) {
            int row = wave * 16 + lg * 4 + r;
            c[r] = m1b[row] + m2b[row];
        }
        acc[nt] = c;
    }
#pragma unroll
    for (int kb = 0; kb < 6; kb++) {
        bf16x8 af = *(const bf16x8*)(mwp + (size_t)((kb * 4 + wave) * 64 + l) * 8);
#pragma unroll
        for (int nt = 0; nt < 4; nt++) {
            bf16x8 bfv = *(const bf16x8*)(Bf + ((size_t)(kb * 4 + nt) * 64 + l) * 8);
            acc[nt] = __builtin_amdgcn_mfma_f32_16x16x32_bf16(af, bfv, acc[nt], 0, 0, 0);
        }
    }
#pragma unroll
    for (int nt = 0; nt < 4; nt++)
#pragma unroll
        for (int r = 0; r < 4; r++) {
            int row = wave * 16 + lg * 4 + r;
            int i2 = row >> 5, o = row & 31;
            mix[(size_t)((b * 32 + o) * 1024 + n) * 256 + (i2 * 2 + xp) * 64 + nt * 16 + lr]
                = f2bf(acc[nt][r]);
        }
}

// fused Wtf1(relu)Wtf2 via bf16 MFMA, in-place on bf16 mix: 32 rows/block; grid = CB*1024
__global__ __launch_bounds__(256) void k_tf(unsigned short* mix, const unsigned short* W1p,
                                            const float* B1, const unsigned short* W2p,
                                            const float* B2) {
    __shared__ unsigned short Abuf[32 * 256];   // bf16, XOR-swizzled
    __shared__ unsigned short Hbuf[32 * 256];
    int t = threadIdx.x;
    int wave = t >> 6, l = t & 63;
    size_t row0 = (size_t)blockIdx.x * 32;
    const uint4* src = (const uint4*)(mix + row0 * 256);
#pragma unroll
    for (int it = 0; it < 4; it++) {
        int f = t + it * 256;                  // 1024 8-u16 chunks
        uint4 raw = src[f];
        int e = f * 8, row = e >> 8, col = e & 255;
        int byte = (row * 512 + col * 2) ^ ((row & 7) << 4);
        *(uint4*)((char*)Abuf + byte) = raw;
    }
    __syncthreads();
    int colg0 = wave * 64;
    int lr = l & 15, lg = l >> 4;
    f32x4 acc[2][4];
#pragma unroll
    for (int nb = 0; nb < 4; nb++) {
        float bv = B1[colg0 + nb * 16 + lr];
        f32x4 c; c[0] = bv; c[1] = bv; c[2] = bv; c[3] = bv;
        acc[0][nb] = c; acc[1][nb] = c;
    }
#pragma unroll
    for (int kb = 0; kb < 8; kb++) {
        int k2 = (kb * 32 + lg * 8) * 2;
        int by0 = (lr * 512 + k2) ^ ((lr & 7) << 4);
        int by1 = ((16 + lr) * 512 + k2) ^ ((lr & 7) << 4);
        bf16x8 a0 = *(const bf16x8*)((char*)Abuf + by0);
        bf16x8 a1 = *(const bf16x8*)((char*)Abuf + by1);
#pragma unroll
        for (int nb = 0; nb < 4; nb++) {
            int nbg = wave * 4 + nb;
            bf16x8 bw = *(const bf16x8*)(W1p + (size_t)((kb * 16 + nbg) * 64 + l) * 8);
            acc[0][nb] = __builtin_amdgcn_mfma_f32_16x16x32_bf16(a0, bw, acc[0][nb], 0, 0, 0);
            acc[1][nb] = __builtin_amdgcn_mfma_f32_16x16x32_bf16(a1, bw, acc[1][nb], 0, 0, 0);
        }
    }
#pragma unroll
    for (int rb = 0; rb < 2; rb++)
#pragma unroll
        for (int nb = 0; nb < 4; nb++)
#pragma unroll
            for (int r = 0; r < 4; r++) {
                int row = rb * 16 + lg * 4 + r;
                int col = colg0 + nb * 16 + lr;
                unsigned short h = f2bf(fmaxf(acc[rb][nb][r], 0.f));
                int byte = (row * 512 + col * 2) ^ ((row & 7) << 4);
                *(unsigned short*)((char*)Hbuf + byte) = h;
            }
    __syncthreads();
#pragma unroll
    for (int nb = 0; nb < 4; nb++) {
        float bv = B2[colg0 + nb * 16 + lr];
        f32x4 c; c[0] = bv; c[1] = bv; c[2] = bv; c[3] = bv;
        acc[0][nb] = c; acc[1][nb] = c;
    }
#pragma unroll
    for (int kb = 0; kb < 8; kb++) {
        int k2 = (kb * 32 + lg * 8) * 2;
        int by0 = (lr * 512 + k2) ^ ((lr & 7) << 4);
        int by1 = ((16 + lr) * 512 + k2) ^ ((lr & 7) << 4);
        bf16x8 a0 = *(const bf16x8*)((char*)Hbuf + by0);
        bf16x8 a1 = *(const bf16x8*)((char*)Hbuf + by1);
#pragma unroll
        for (int nb = 0; nb < 4; nb++) {
            int nbg = wave * 4 + nb;
            bf16x8 bw = *(const bf16x8*)(W2p + (size_t)((kb * 16 + nbg) * 64 + l) * 8);
            acc[0][nb] = __builtin_amdgcn_mfma_f32_16x16x32_bf16(a0, bw, acc[0][nb], 0, 0, 0);
            acc[1][nb] = __builtin_amdgcn_mfma_f32_16x16x32_bf16(a1, bw, acc[1][nb], 0, 0, 0);
        }
    }
#pragma unroll
    for (int rb = 0; rb < 2; rb++)
#pragma unroll
        for (int nb = 0; nb < 4; nb++)
#pragma unroll
            for (int r = 0; r < 4; r++) {
                int row = rb * 16 + lg * 4 + r;
                int col = colg0 + nb * 16 + lr;
                mix[(row0 + row) * 256 + col] = f2bf(acc[rb][nb][r]);
            }
}

// fused ec1(relu)+ec2 via bf16 MFMA; bf16 mix in, bf16 eco out; grid = CB*1024
__global__ __launch_bounds__(256) void k_ec(const unsigned short* tfo,
        const unsigned short* W1p, const float* B1,
        const unsigned short* W2p, const float* B2, unsigned short* eco) {
    __shared__ unsigned short Hl[4 * 64 * 48];   // per-wave [64 l][48 u16] = 24 KB
    int t = threadIdx.x;
    int wave = t >> 6, l = t & 63;
    int lr = l & 15, lg = l >> 4;
    int b = blockIdx.x >> 10, n = blockIdx.x & 1023;
    int lbase = wave * 64;
    unsigned short* myH = Hl + wave * 3072;
    const unsigned short* xb = tfo + ((size_t)(b * 32) * 1024 + n) * 256;
    bf16x8 xf[4];
#pragma unroll
    for (int nt = 0; nt < 4; nt++) {
        int ll = lbase + nt * 16 + lr;
        bf16x8 v;
#pragma unroll
        for (int j = 0; j < 8; j++)
            v[j] = (short)xb[(size_t)(lg * 8 + j) * 262144 + ll];
        xf[nt] = v;
    }
    f32x4 d2[4];
    {
        f32x4 c;
#pragma unroll
        for (int r = 0; r < 4; r++) {
            int p = lg * 4 + r;
            c[r] = (p < 12) ? B2[p] : 0.f;
        }
#pragma unroll
        for (int nt = 0; nt < 4; nt++) d2[nt] = c;
    }
#pragma unroll
    for (int ch = 0; ch < 4; ch++) {
        f32x4 h[2][4];
#pragma unroll
        for (int mt = 0; mt < 2; mt++) {
            f32x4 c;
#pragma unroll
            for (int r = 0; r < 4; r++) c[r] = B1[ch * 32 + mt * 16 + lg * 4 + r];
#pragma unroll
            for (int nt = 0; nt < 4; nt++) h[mt][nt] = c;
        }
#pragma unroll
        for (int mt = 0; mt < 2; mt++) {
            bf16x8 aw = *(const bf16x8*)(W1p + (size_t)((ch * 2 + mt) * 64 + l) * 8);
#pragma unroll
            for (int nt = 0; nt < 4; nt++)
                h[mt][nt] = __builtin_amdgcn_mfma_f32_16x16x32_bf16(aw, xf[nt], h[mt][nt], 0, 0, 0);
        }
#pragma unroll
        for (int mt = 0; mt < 2; mt++)
#pragma unroll
            for (int nt = 0; nt < 4; nt++) {
                unsigned lo = f2bf(fmaxf(h[mt][nt][0], 0.f)) |
                              ((unsigned)f2bf(fmaxf(h[mt][nt][1], 0.f)) << 16);
                unsigned hi = f2bf(fmaxf(h[mt][nt][2], 0.f)) |
                              ((unsigned)f2bf(fmaxf(h[mt][nt][3], 0.f)) << 16);
                uint2 pk; pk.x = lo; pk.y = hi;
                *(uint2*)(myH + (nt * 16 + lr) * 48 + mt * 16 + lg * 4) = pk;
            }
        bf16x8 aw2 = *(const bf16x8*)(W2p + (size_t)(ch * 64 + l) * 8);
#pragma unroll
        for (int nt = 0; nt < 4; nt++) {
            bf16x8 hf = *(const bf16x8*)(myH + (nt * 16 + lr) * 48 + lg * 8);
            d2[nt] = __builtin_amdgcn_mfma_f32_16x16x32_bf16(aw2, hf, d2[nt], 0, 0, 0);
        }
    }
#pragma unroll
    for (int nt = 0; nt < 4; nt++)
#pragma unroll
        for (int r = 0; r < 4; r++) {
            int p = lg * 4 + r;
            if (p < 12) {
                int ll = lbase + nt * 16 + lr;
                eco[((size_t)(b * 12 + p) * 1024 + n) * 256 + ll] = f2bf(d2[nt][r]);
            }
        }
}

// stage relu(fh) into MFMA A-frag order: apk[(rg*15+kb)*64+lane][8]
// streaming, fully-coalesced writes; grid = CB*2880
__global__ __launch_bounds__(256) void k_stage(const unsigned short* gated,
        const unsigned short* eco, const unsigned short* hd_emb,
        const float* hist, const float* tide, const float* diwe,
        unsigned short* apk) {
    int id = blockIdx.x * 256 + threadIdx.x;
    int lane = id & 63, rest = id >> 6;
    int rg = rest / 15, kb = rest - rg * 15;    // kb wave-uniform
    int lr = lane & 15, lg = lane >> 4;
    int grow = rg * 16 + lr;
    int n = grow & 1023, bt = grow >> 10;
    int b = bt / 12, tt = bt - b * 12;
    int off = kb * 32 + lg * 8;
    bf16x8 v;
    if (kb <= 3) {
        v = relu8(*(const bf16x8*)(gated + (size_t)grow * 128 + off));
    } else if (kb <= 11) {
        v = relu8(*(const bf16x8*)(eco + (size_t)((b * 12 + tt) * 1024 + n) * 256 + off - 128));
    } else if (kb == 12) {
        int tid_i = (int)(hist[(size_t)grow * 4 + 2] * 288.0f);
        int diw_i = (int)hist[(size_t)grow * 4 + 3];
        const unsigned short* hptr = hd_emb + (size_t)grow * 64;
#pragma unroll
        for (int j = 0; j < 8; j++) {
            int k = off + j;                    // in [384, 416)
            float x;
            if (k < 396) x = tide[tid_i * 12 + k - 384];
            else if (k < 408) x = diwe[diw_i * 12 + k - 396];
            else x = bf2f(hptr[k - 408]);
            v[j] = (short)f2bf(fmaxf(x, 0.f));
        }
    } else if (kb == 13) {
        v = relu8(*(const bf16x8*)(hd_emb + (size_t)grow * 64 + off - 408));
    } else {                                    // kb == 14
        if (lg < 3) v = relu8(*(const bf16x8*)(hd_emb + (size_t)grow * 64 + off - 408));
        else {
#pragma unroll
            for (int j = 0; j < 8; j++) v[j] = 0;
        }
    }
    *(bf16x8*)(apk + (size_t)id * 8) = v;
}

// fc1(bf16 MFMA)+relu+fc2: ALL loads contiguous (A pre-packed by k_stage).
// 32 rows/block (two 16-row A-groups share every weight fetch), 4 waves x 128 cols;
// wave partials to pbuf; grid = CB*384
__global__ __launch_bounds__(256) void k_fc(const unsigned short* apk,
        const unsigned short* W1p, const float* B1, const float* W2,
        float* pbuf) {
    int t = threadIdx.x;
    int wave = t >> 6, l = t & 63;
    int lr = l & 15, lg = l >> 4;
    int rg0 = blockIdx.x * 2;
    int colg0 = wave * 128;
    f32x4 acc[2][8];
#pragma unroll
    for (int nb = 0; nb < 8; nb++) {
        float bv = B1[colg0 + nb * 16 + lr];
        f32x4 c; c[0] = bv; c[1] = bv; c[2] = bv; c[3] = bv;
        acc[0][nb] = c; acc[1][nb] = c;
    }
#pragma unroll
    for (int kb = 0; kb < 15; kb++) {
        bf16x8 af0 = *(const bf16x8*)(apk + (size_t)((rg0 * 15 + kb) * 64 + l) * 8);
        bf16x8 af1 = *(const bf16x8*)(apk + (size_t)(((rg0 + 1) * 15 + kb) * 64 + l) * 8);
#pragma unroll
        for (int nb = 0; nb < 8; nb++) {
            bf16x8 bw = *(const bf16x8*)(W1p + (size_t)((kb * 32 + wave * 8 + nb) * 64 + l) * 8);
            acc[0][nb] = __builtin_amdgcn_mfma_f32_16x16x32_bf16(af0, bw, acc[0][nb], 0, 0, 0);
            acc[1][nb] = __builtin_amdgcn_mfma_f32_16x16x32_bf16(af1, bw, acc[1][nb], 0, 0, 0);
        }
    }
    // ---- fc2: relu(acc) in fp32, in-register partials over this wave's 128 cols ----
    float p[2][4][3];
#pragma unroll
    for (int rr = 0; rr < 2; rr++)
#pragma unroll
        for (int r = 0; r < 4; r++) { p[rr][r][0] = 0.f; p[rr][r][1] = 0.f; p[rr][r][2] = 0.f; }
#pragma unroll
    for (int nb = 0; nb < 8; nb++) {
        int col = colg0 + nb * 16 + lr;
        float w0 = W2[col * 3], w1 = W2[col * 3 + 1], w2 = W2[col * 3 + 2];
#pragma unroll
        for (int rr = 0; rr < 2; rr++)
#pragma unroll
            for (int r = 0; r < 4; r++) {
                float h = fmaxf(acc[rr][nb][r], 0.f);
                p[rr][r][0] += h * w0; p[rr][r][1] += h * w1; p[rr][r][2] += h * w2;
            }
    }
#pragma unroll
    for (int off = 8; off >= 1; off >>= 1)
#pragma unroll
        for (int rr = 0; rr < 2; rr++)
#pragma unroll
            for (int r = 0; r < 4; r++) {
                p[rr][r][0] += __shfl_xor(p[rr][r][0], off);
                p[rr][r][1] += __shfl_xor(p[rr][r][1], off);
                p[rr][r][2] += __shfl_xor(p[rr][r][2], off);
            }
    if (lr == 0) {
#pragma unroll
        for (int rr = 0; rr < 2; rr++)
#pragma unroll
            for (int r = 0; r < 4; r++) {
                size_t gr = (size_t)((rg0 + rr) * 16 + lg * 4 + r);
#pragma unroll
                for (int pp = 0; pp < 3; pp++)
                    pbuf[gr * 12 + wave * 3 + pp] = p[rr][r][pp];
            }
    }
}

// final: sum 4 wave-partials + fc2 bias, conv1x1 over time, transpose; grid = CB*48
__global__ void k_ec3(const float* pbuf, const float* B2, const float* W, const float* bv,
                      float* out) {
    int idx = blockIdx.x * 256 + threadIdx.x;
    int l = idx % 3;
    int rest = idx / 3;
    int o = rest & 3;
    int n = (rest >> 2) & 1023;
    int b = rest >> 12;
    float s = bv[o];
#pragma unroll
    for (int c = 0; c < 12; c++) {
        const float* pb = pbuf + ((size_t)(b * 12 + c) * 1024 + n) * 12;
        float fv = B2[l] + pb[l] + pb[3 + l] + pb[6 + l] + pb[9 + l];
        s += fv * W[o * 12 + c];
    }
    out[idx] = s;
}

// ---------------- launcher ----------------
extern "C" void kernel_launch(void* const* d_in, const int* in_sizes, int n_in,
                              void* d_out, int out_size, void* d_ws, size_t ws_size,
                              hipStream_t stream) {
    const float* hist = (const float*)d_in[0];
    const float* node_emb_u = (const float*)d_in[1];
    const float* T_i_D_emb = (const float*)d_in[2];
    const float* D_i_W_emb = (const float*)d_in[3];
    const float* gc_emb1 = (const float*)d_in[4];
    const float* gc_emb2 = (const float*)d_in[5];
    const float* gc_w1 = (const float*)d_in[6];
    const float* gc_b1 = (const float*)d_in[7];
    const float* gc_w2 = (const float*)d_in[8];
    const float* gc_b2 = (const float*)d_in[9];
    const float* W_emb = (const float*)d_in[10];
    const float* b_emb = (const float*)d_in[11];
    const float* Wg1 = (const float*)d_in[12];
    const float* bg1 = (const float*)d_in[13];
    const float* Wg2 = (const float*)d_in[14];
    const float* bg2 = (const float*)d_in[15];
    const float* Wsc = (const float*)d_in[16];
    const float* bsc = (const float*)d_in[17];
    const float* mix1_w = (const float*)d_in[18];
    const float* mix1_b = (const float*)d_in[19];
    const float* mix2_w = (const float*)d_in[20];
    const float* mix2_b = (const float*)d_in[21];
    const float* Wtf1 = (const float*)d_in[22];
    const float* btf1 = (const float*)d_in[23];
    const float* Wtf2 = (const float*)d_in[24];
    const float* btf2 = (const float*)d_in[25];
    const float* Wec1 = (const float*)d_in[26];
    const float* bec1 = (const float*)d_in[27];
    const float* Wec2 = (const float*)d_in[28];
    const float* bec2 = (const float*)d_in[29];
    const float* Wfc1 = (const float*)d_in[30];
    const float* bfc1 = (const float*)d_in[31];
    const float* Wfc2 = (const float*)d_in[32];
    const float* bfc2 = (const float*)d_in[33];
    const float* Wec3 = (const float*)d_in[34];
    const float* bec3 = (const float*)d_in[35];

    float* ws = (float*)d_ws;
    float* n1 = ws + F_N1;
    float* n2 = ws + F_N2;
    float* aN_val = ws + F_ANVAL;
    float* row_val = ws + F_ROWVAL;
    float* col_sum = ws + F_COLSUM;
    float* inv_cs = ws + F_INVCS;
    float* aT_val = ws + F_ATVAL;
    int* aN_idx = (int*)(ws + I_ANIDX);
    int* row_idx = (int*)(ws + I_ROWIDX);
    int* col_cnt = (int*)(ws + I_COLCNT);
    int* col_off = (int*)(ws + I_COLOFF);
    int* col_fill = (int*)(ws + I_COLFILL);
    int* aT_idx = (int*)(ws + I_ATIDX);
    unsigned short* w1p = (unsigned short*)(ws + F_W1P);
    unsigned short* w2p = (unsigned short*)(ws + F_W2P);
    unsigned short* wfcp = (unsigned short*)(ws + F_WFCP);
    unsigned short* wec1p = (unsigned short*)(ws + F_WEC1P);
    unsigned short* wec2p = (unsigned short*)(ws + F_WEC2P);
    unsigned short* wmwp = (unsigned short*)(ws + F_WMWP);

    // pick largest batch-chunk CB that fits the workspace
    size_t avail = ws_size / 4;   // floats
    int CB = 8;
    while (CB > 1 && GRAPH_FLOATS + (size_t)CB * PB_TOTAL > avail) CB >>= 1;
    int nchunk = 8 / CB;

    size_t xstride = (size_t)CB * PB_X * 2;     // u16 per xp slab
    unsigned short* gated = (unsigned short*)(ws + GRAPH_FLOATS);
    unsigned short* hd_emb = (unsigned short*)(ws + GRAPH_FLOATS + (size_t)CB * PB_GATED);
    unsigned short* xs = (unsigned short*)(ws + GRAPH_FLOATS + (size_t)CB * (PB_GATED + PB_HD));
    unsigned short* h1 = xs + 2 * xstride;
    unsigned short* h2 = h1 + 2 * xstride;
    unsigned short* h1b = h2 + 2 * xstride;
    unsigned short* h2b = h1b + 2 * xstride;
    unsigned short* mix = h2b + 2 * xstride;
    unsigned short* apk = mix;       // alias: mix dead after k_ec; apk < mix size
    unsigned short* eco = xs;        // alias: xs(2 slabs = CB*4M u16) >= eco (CB*3M u16)
    float* fbuf = (float*)h2b;       // alias: h2b dead by k_fc (CB*147456 f32 partials)

    // ---- graph construction + weight packing (once) ----
    k_init<<<4, 256, 0, stream>>>(col_cnt, col_fill, col_sum);
    k_embed<<<320, 256, 0, stream>>>(gc_emb1, gc_emb2, gc_w1, gc_b1, gc_w2, gc_b2, n1, n2);
    k_adj<<<1024, 256, 0, stream>>>(n1, n2, aN_val, aN_idx, row_val, row_idx, col_cnt, col_sum);
    k_scan<<<1, 1024, 0, stream>>>(col_cnt, col_off, col_sum, inv_cs);
    k_scatter<<<40, 256, 0, stream>>>(row_idx, row_val, col_off, col_fill, aT_idx, aT_val);
    k_packw<<<32, 256, 0, stream>>>(Wtf1, w1p);
    k_packw<<<32, 256, 0, stream>>>(Wtf2, w2p);
    k_packfc<<<120, 256, 0, stream>>>(Wfc1, wfcp);
    k_packec<<<3, 256, 0, stream>>>(Wec1, Wec2, wec1p, wec2p);
    k_packmw<<<6, 256, 0, stream>>>(mix1_w, mix2_w, wmwp);

    // ---- per-chunk pipeline ----
    for (int ch = 0; ch < nchunk; ch++) {
        const float* hist_c = hist + (size_t)ch * CB * ROWS_PER_B * 4;
        float* out_c = (float*)d_out + (size_t)ch * CB * ROWS_PER_B;

        k_gate<<<CB * 768, 256, 0, stream>>>(hist_c, node_emb_u, T_i_D_emb, D_i_W_emb,
                                             Wg1, bg1, Wg2, bg2, W_emb, b_emb, gated, hd_emb);
        k_wsc<<<dim3(CB * 256, 2), 256, 0, stream>>>(gated, Wsc, bsc, xs, xstride);
        k_spmm2<<<dim3(CB * 1024, 4), 256, 0, stream>>>(h1, h1b, xs, xs, xs,
                                                        aN_idx, aN_val, aT_idx, aT_val,
                                                        col_off, inv_cs, xstride);
        k_spmm2<<<dim3(CB * 1024, 4), 256, 0, stream>>>(h2, h2b, xs, h1, h1b,
                                                        aN_idx, aN_val, aT_idx, aT_val,
                                                        col_off, inv_cs, xstride);
        k_proj<<<dim3(CB * 1024, 2), 256, 0, stream>>>(xs, h1, h2, h1b, h2b,
                                                       wmwp, mix1_b, mix2_b, mix, xstride);
        k_tf<<<CB * 1024, 256, 0, stream>>>(mix, w1p, btf1, w2p, btf2);
        k_ec<<<CB * 1024, 256, 0, stream>>>(mix, wec1p, bec1, wec2p, bec2, eco);
        k_stage<<<CB * 2880, 256, 0, stream>>>(gated, eco, hd_emb, hist_c,
                                               T_i_D_emb, D_i_W_emb, apk);
        k_fc<<<CB * 384, 256, 0, stream>>>(apk, wfcp, bfc1, Wfc2, fbuf);
        k_ec3<<<CB * 48, 256, 0, stream>>>(fbuf, bfc2, Wec3, bec3, out_c);
    }
}

// Round 27
// 1012.852 us; speedup vs baseline: 1.0259x; 1.0259x over previous
//
#include <hip/hip_runtime.h>
#include <math.h>

// ---------------- constants ----------------
constexpr int ROWS_PER_B = 12 * 1024;    // rows (b,t,n) per batch element

// ---------------- graph workspace (float offsets, < 524288) ----------------
constexpr size_t F_N1 = 0;              // 1024*40
constexpr size_t F_N2 = 40960;
constexpr size_t F_ANVAL = 81920;       // 1024*11
constexpr size_t F_ROWVAL = 93184;      // 1024*10
constexpr size_t F_COLSUM = 103424;     // 1024
constexpr size_t F_INVCS = 104448;      // 1024
constexpr size_t F_ATVAL = 105472;      // 10240
constexpr size_t I_ANIDX = 115712;      // ints stored in float slots
constexpr size_t I_ROWIDX = 126976;
constexpr size_t I_COLCNT = 137216;
constexpr size_t I_COLOFF = 138240;     // 1025
constexpr size_t I_COLFILL = 139265;
constexpr size_t I_ATIDX = 140289;      // ends 150529
constexpr size_t F_W1P = 151552;        // packed bf16 Wtf1: 32768 floats
constexpr size_t F_W2P = 184320;        // packed bf16 Wtf2: ends 217088
constexpr size_t F_WFCP = 217088;       // packed bf16 Wfc1: ends 339968
constexpr size_t F_WEC1P = 339968;      // packed bf16 Wec1
constexpr size_t F_WEC2P = 342016;      // packed bf16 Wec2 -> ends 343040
constexpr size_t F_WMWP = 343040;       // packed bf16 mix weights -> ends 349184
constexpr size_t GRAPH_FLOATS = 524288;

// per-chunk float-unit counts (per batch element) — bf16 storage
constexpr size_t PB_GATED = (size_t)ROWS_PER_B * 128 / 2;   // 786432
constexpr size_t PB_HD = (size_t)ROWS_PER_B * 64 / 2;       // 393216
constexpr size_t PB_X = (size_t)32 * 1024 * 64 / 2;         // 1048576 per xp slab
constexpr size_t PB_MIX = (size_t)32 * 1024 * 256 / 2;      // 4194304
// x-chain is double-buffered over xp (xs,h1,h2,h1b,h2b each x2); apk aliases mix
constexpr size_t PB_TOTAL = PB_GATED + PB_HD + 10 * PB_X + PB_MIX; // 15859712

typedef __attribute__((ext_vector_type(8))) short bf16x8;
typedef __attribute__((ext_vector_type(4))) float f32x4;

__device__ __forceinline__ unsigned short f2bf(float f) {
    unsigned u = __float_as_uint(f);
    unsigned r = (u + 0x7fffu + ((u >> 16) & 1u)) >> 16;   // RNE
    return (unsigned short)r;
}
__device__ __forceinline__ float bf2f(unsigned short h) {
    return __uint_as_float((unsigned)h << 16);
}
__device__ __forceinline__ void unpack8(uint4 raw, float* f) {
    f[0] = bf2f((unsigned short)(raw.x & 0xffff)); f[1] = bf2f((unsigned short)(raw.x >> 16));
    f[2] = bf2f((unsigned short)(raw.y & 0xffff)); f[3] = bf2f((unsigned short)(raw.y >> 16));
    f[4] = bf2f((unsigned short)(raw.z & 0xffff)); f[5] = bf2f((unsigned short)(raw.z >> 16));
    f[6] = bf2f((unsigned short)(raw.w & 0xffff)); f[7] = bf2f((unsigned short)(raw.w >> 16));
}
__device__ __forceinline__ uint4 pack8(const float* f) {
    uint4 r;
    r.x = f2bf(f[0]) | ((unsigned)f2bf(f[1]) << 16);
    r.y = f2bf(f[2]) | ((unsigned)f2bf(f[3]) << 16);
    r.z = f2bf(f[4]) | ((unsigned)f2bf(f[5]) << 16);
    r.w = f2bf(f[6]) | ((unsigned)f2bf(f[7]) << 16);
    return r;
}
__device__ __forceinline__ bf16x8 relu8(bf16x8 v) {
#pragma unroll
    for (int j = 0; j < 8; j++) {
        unsigned short u = (unsigned short)v[j];
        v[j] = (short)((u >> 15) ? 0 : u);
    }
    return v;
}

// ---------------- graph kernels ----------------

__global__ void k_init(int* cnt, int* fill, float* csum) {
    int t = blockIdx.x * 256 + threadIdx.x;
    if (t < 1024) { cnt[t] = 0; fill[t] = 0; csum[t] = 0.f; }
}

__global__ void k_embed(const float* e1, const float* e2, const float* w1, const float* b1,
                        const float* w2, const float* b2, float* n1, float* n2) {
    int idx = blockIdx.x * 256 + threadIdx.x;   // < 81920
    if (idx >= 81920) return;
    int m = idx / 40960, rem = idx - m * 40960;
    int i = rem / 40, j = rem - i * 40;
    const float* e = m ? e2 : e1;
    const float* w = m ? w2 : w1;
    const float* bv = m ? b2 : b1;
    float a = bv[j];
    for (int k = 0; k < 40; k++) a += e[i * 40 + k] * w[k * 40 + j];
    (m ? n2 : n1)[i * 40 + j] = tanhf(3.0f * a);
}

__global__ __launch_bounds__(256) void k_adj(const float* n1, const float* n2,
        float* aN_val, int* aN_idx, float* row_val, int* row_idx,
        int* col_cnt, float* col_sum) {
    __shared__ float arow[1024];
    __shared__ float n1v[40], n2v[40];
    __shared__ float rv[256];
    __shared__ int ri[256];
    __shared__ float topv[10];
    __shared__ int topi[10];
    int v = blockIdx.x, t = threadIdx.x;
    if (t < 40) { n1v[t] = n1[v * 40 + t]; n2v[t] = n2[v * 40 + t]; }
    __syncthreads();
    for (int j = t; j < 1024; j += 256) {
        float d1 = 0.f, d2 = 0.f;
        for (int k = 0; k < 40; k++) {
            d1 += n1v[k] * n2[j * 40 + k];
            d2 += n2v[k] * n1[j * 40 + k];
        }
        float a = tanhf(3.0f * (d1 - d2));
        arow[j] = a > 0.f ? a : 0.f;
    }
    __syncthreads();
    for (int r = 0; r < 10; r++) {
        float bv = -1.f; int bi = 1 << 30;
        for (int j = t; j < 1024; j += 256) {
            float x = arow[j];
            if (x > bv || (x == bv && j < bi)) { bv = x; bi = j; }
        }
        rv[t] = bv; ri[t] = bi;
        __syncthreads();
        for (int s = 128; s > 0; s >>= 1) {
            if (t < s) {
                float ov = rv[t + s]; int oi = ri[t + s];
                if (ov > rv[t] || (ov == rv[t] && oi < ri[t])) { rv[t] = ov; ri[t] = oi; }
            }
            __syncthreads();
        }
        if (t == 0) { topv[r] = rv[0]; topi[r] = ri[0]; arow[ri[0]] = -1.f; }
        __syncthreads();
    }
    if (t == 0) {
        float s = 1.f;
        for (int r = 0; r < 10; r++) s += topv[r];
        float inv = 1.f / s;
        for (int r = 0; r < 10; r++) {
            aN_idx[v * 11 + r] = topi[r];
            aN_val[v * 11 + r] = topv[r] * inv;
            row_idx[v * 10 + r] = topi[r];
            row_val[v * 10 + r] = topv[r];
            atomicAdd(&col_cnt[topi[r]], 1);
            atomicAdd(&col_sum[topi[r]], topv[r]);
        }
        aN_idx[v * 11 + 10] = v;
        aN_val[v * 11 + 10] = inv;
    }
}

__global__ __launch_bounds__(1024) void k_scan(const int* cnt, int* off,
                                               const float* csum, float* inv) {
    __shared__ int tmp[1024];
    int t = threadIdx.x;
    tmp[t] = cnt[t];
    __syncthreads();
    for (int s = 1; s < 1024; s <<= 1) {
        int v = 0;
        if (t >= s) v = tmp[t - s];
        __syncthreads();
        tmp[t] += v;
        __syncthreads();
    }
    off[t + 1] = tmp[t];
    if (t == 0) off[0] = 0;
    inv[t] = 1.0f / (csum[t] + 1.0f);
}

__global__ void k_scatter(const int* row_idx, const float* row_val, const int* off,
                          int* fill, int* aT_idx, float* aT_val) {
    int e = blockIdx.x * 256 + threadIdx.x;
    if (e >= 10240) return;
    int v = e / 10;
    int j = row_idx[e];
    int pos = off[j] + atomicAdd(&fill[j], 1);
    aT_idx[pos] = v;
    aT_val[pos] = row_val[e];
}

// pack 256x256 f32 weight into MFMA B-fragment order
__global__ void k_packw(const float* W, unsigned short* out) {
    int id = blockIdx.x * 256 + threadIdx.x;    // 8192 total
    if (id >= 8192) return;
    int lane = id & 63, rest = id >> 6;
    int nb = rest & 15, kb = rest >> 4;
    int krow = kb * 32 + (lane >> 4) * 8;
    int col = nb * 16 + (lane & 15);
    unsigned short v[8];
#pragma unroll
    for (int j = 0; j < 8; j++) v[j] = f2bf(W[(size_t)(krow + j) * 256 + col]);
#pragma unroll
    for (int j = 0; j < 8; j++) out[(size_t)id * 8 + j] = v[j];
}

// pack 472x512 Wfc1 into B-fragment order, K padded to 480
__global__ void k_packfc(const float* W, unsigned short* out) {
    int id = blockIdx.x * 256 + threadIdx.x;    // 30720 total
    if (id >= 30720) return;
    int lane = id & 63, rest = id >> 6;
    int nb = rest & 31, kb = rest >> 5;         // kb < 15
    int k0 = kb * 32 + (lane >> 4) * 8;
    int col = nb * 16 + (lane & 15);
    unsigned short v[8];
#pragma unroll
    for (int j = 0; j < 8; j++) {
        int k = k0 + j;
        v[j] = (k < 472) ? f2bf(W[(size_t)k * 512 + col]) : (unsigned short)0;
    }
#pragma unroll
    for (int j = 0; j < 8; j++) out[(size_t)id * 8 + j] = v[j];
}

// pack Wec1 (128x32) and Wec2 (12x128, pad 16) into A-frag order
__global__ void k_packec(const float* W1, const float* W2,
                         unsigned short* o1, unsigned short* o2) {
    int id = blockIdx.x * 256 + threadIdx.x;    // 768 total
    if (id < 512) {
        int mt = id >> 6, lane = id & 63;
        int o = mt * 16 + (lane & 15);
        int c0 = (lane >> 4) * 8;
#pragma unroll
        for (int j = 0; j < 8; j++)
            o1[(size_t)id * 8 + j] = f2bf(W1[o * 32 + c0 + j]);
    } else if (id < 768) {
        int id2 = id - 512;
        int kb = id2 >> 6, lane = id2 & 63;
        int p = lane & 15;
        int k0 = kb * 32 + (lane >> 4) * 8;
#pragma unroll
        for (int j = 0; j < 8; j++)
            o2[(size_t)id2 * 8 + j] = (p < 12) ? f2bf(W2[p * 128 + k0 + j])
                                               : (unsigned short)0;
    }
}

// pack mix weights [64 rows][192 K] into A-frag order (24 frags)
__global__ void k_packmw(const float* mw1, const float* mw2, unsigned short* out) {
    int id = blockIdx.x * 256 + threadIdx.x;    // 1536 total
    if (id >= 1536) return;
    int f = id >> 6, lane = id & 63;
    int kb = f >> 2, rt = f & 3;
    int row = rt * 16 + (lane & 15);
    int ph = (kb >= 3) ? 1 : 0;
    int kloc = (kb - ph * 3) * 32 + (lane >> 4) * 8;
    const float* mw = ph ? mw2 : mw1;
#pragma unroll
    for (int j = 0; j < 8; j++)
        out[(size_t)id * 8 + j] = f2bf(mw[row * 96 + kloc + j]);
}

// ---------------- per-chunk kernels ----------------

// gate MLP + embed; 16 rows/block (weights staged once, float4); grid = CB*768
__global__ __launch_bounds__(256) void k_gate(const float* hist, const float* nodeu,
        const float* tide, const float* diwe,
        const float* Wg1, const float* bg1, const float* Wg2, const float* bg2,
        const float* Wemb, const float* bemb, unsigned short* gated, unsigned short* hd_emb) {
    __shared__ float w1[4096], w2[4096];
    __shared__ float gin[4][64], hid[4][64];
    __shared__ float sb1[64], sb2[64], we[128], be[64];
    int t = threadIdx.x;
    for (int i = t; i < 1024; i += 256) {
        ((float4*)w1)[i] = ((const float4*)Wg1)[i];
        ((float4*)w2)[i] = ((const float4*)Wg2)[i];
    }
    if (t < 64) { sb1[t] = bg1[t]; sb2[t] = bg2[t]; be[t] = bemb[t]; }
    if (t < 128) we[t] = Wemb[t];
    int r = t >> 6, lane = t & 63;
    __syncthreads();
#pragma unroll
    for (int it = 0; it < 4; it++) {
        int row = blockIdx.x * 16 + it * 4 + r;
        int n = row & 1023;
        const float* hrow = hist + (size_t)row * 4;
        float f0 = hrow[0], f1 = hrow[1];
        int tid_i = (int)(hrow[2] * 288.0f);
        int diw_i = (int)hrow[3];
        float g;
        if (lane < 40) g = nodeu[n * 40 + lane];
        else if (lane < 52) g = tide[tid_i * 12 + lane - 40];
        else g = diwe[diw_i * 12 + lane - 52];
        gin[r][lane] = g;
        __syncthreads();
        float acc = sb1[lane];
        for (int k = 0; k < 64; k++) acc += gin[r][k] * w1[k * 64 + lane];
        hid[r][lane] = acc > 0.f ? acc : 0.f;
        __syncthreads();
        acc = sb2[lane];
        for (int k = 0; k < 64; k++) acc += hid[r][k] * w2[k * 64 + lane];
        float gate = 1.f / (1.f + expf(-acc));
        float hd = f0 * we[lane] + f1 * we[64 + lane] + be[lane];
        float x1 = gate * hd;
        gated[(size_t)row * 128 + lane] = f2bf(x1);
        gated[(size_t)row * 128 + 64 + lane] = f2bf(hd - x1);
        hd_emb[(size_t)row * 64 + lane] = f2bf(hd);
        __syncthreads();
    }
}

// xs = relu(sum_t gated*Wsc + bsc), both xp halves; grid = dim3(CB*256, 2)
__global__ __launch_bounds__(256) void k_wsc(const unsigned short* gated, const float* Wsc,
                                             const float* bsc, unsigned short* xs,
                                             size_t xstride) {
    __shared__ float w[384];
    __shared__ float sb[32];
    int t = threadIdx.x;
    if (t < 384) w[t] = Wsc[t];
    if (t < 32) sb[t] = bsc[t];
    __syncthreads();
    int xoff = blockIdx.y * 64;
    unsigned short* out = xs + (size_t)blockIdx.y * xstride;
    int idx = blockIdx.x * 256 + t;
    int h = idx & 63, n = (idx >> 6) & 1023, b = idx >> 16;
    float xv[12];
#pragma unroll
    for (int tt = 0; tt < 12; tt++)
        xv[tt] = bf2f(gated[(size_t)((b * 12 + tt) * 1024 + n) * 128 + xoff + h]);
#pragma unroll
    for (int o = 0; o < 32; o++) {
        float a = sb[o];
#pragma unroll
        for (int tt = 0; tt < 12; tt++) a += xv[tt] * w[o * 12 + tt];
        out[(size_t)((b * 32 + o) * 1024 + n) * 64 + h] = f2bf(a > 0.f ? a : 0.f);
    }
}

// fused dual spmm, split by PATH: blockIdx.y = xp*2 + path.
// path0: out1 = .05x + .95*aN@hin1 (11 gathers); path1: out2 = .05x + .95*aTN@hin2
// (16 prefetched + tail). Same per-element arithmetic/order as the fused version
// -> bit-identical. Halved per-thread latency chain, 2x blocks for TLP.
// bf16 in/out; XCD-swizzled. grid = dim3(CB*1024, 4)
__global__ __launch_bounds__(256) void k_spmm2(unsigned short* out1, unsigned short* out2,
        const unsigned short* x, const unsigned short* hin1, const unsigned short* hin2,
        const int* aN_idx, const float* aN_val,
        const int* aT_idx, const float* aT_val,
        const int* off, const float* inv_cs, size_t xstride) {
    int xp = blockIdx.y >> 1, path = blockIdx.y & 1;
    size_t xoffs = (size_t)xp * xstride;
    x += xoffs;
    int nper = gridDim.x >> 3;
    int bid = (blockIdx.x & 7) * nper + (blockIdx.x >> 3);   // same-bc blocks -> same XCD
    int t = threadIdx.x;
    int l8 = t & 7, r = t >> 3;             // 32 rows x 8 16B-lanes
    int g = bid * 32 + r;
    int v = g & 1023, bc = g >> 10;
    size_t rowoff = (size_t)bc * 65536;
    float hv[8], s[8], o[8];
    if (path == 0) {
        // ---- aN path (11 fixed edges, independent gathers) ----
        const unsigned short* base1 = hin1 + xoffs + rowoff;
#pragma unroll
        for (int j = 0; j < 8; j++) s[j] = 0.f;
#pragma unroll
        for (int e = 0; e < 11; e++) {
            int w = aN_idx[v * 11 + e];
            float a = aN_val[v * 11 + e];
            uint4 raw = *(const uint4*)(base1 + (size_t)w * 64 + l8 * 8);
            unpack8(raw, hv);
#pragma unroll
            for (int j = 0; j < 8; j++) s[j] += a * hv[j];
        }
        uint4 xr = *(const uint4*)(x + (size_t)g * 64 + l8 * 8);
        float xv[8];
        unpack8(xr, xv);
#pragma unroll
        for (int j = 0; j < 8; j++) o[j] = 0.05f * xv[j] + 0.95f * s[j];
        *(uint4*)(out1 + xoffs + (size_t)g * 64 + l8 * 8) = pack8(o);
    } else {
        // ---- aTN path: 16 prefetched independent gathers (ascending e) + tail ----
        int e0 = off[v], e1 = off[v + 1];
        int ti[16]; float tv[16];
#pragma unroll
        for (int k = 0; k < 16; k++) {
            int e = e0 + k;
            int es = (e < e1) ? e : e0;          // clamp: always a valid address
            ti[k] = aT_idx[es];
            tv[k] = (e < e1) ? aT_val[es] : 0.f; // padding weight 0 -> no-op accumulate
        }
        const unsigned short* base2 = hin2 + xoffs + rowoff;
        uint4 raw = *(const uint4*)(base2 + (size_t)v * 64 + l8 * 8);
        unpack8(raw, s);
#pragma unroll
        for (int k = 0; k < 16; k++) {
            float a = tv[k];
            uint4 rw = *(const uint4*)(base2 + (size_t)ti[k] * 64 + l8 * 8);
            unpack8(rw, hv);
#pragma unroll
            for (int j = 0; j < 8; j++) s[j] += a * hv[j];
        }
        for (int e = e0 + 16; e < e1; e++) {   // rare tail (degree > 16)
            int w = aT_idx[e];
            float a = aT_val[e];
            uint4 rw = *(const uint4*)(base2 + (size_t)w * 64 + l8 * 8);
            unpack8(rw, hv);
#pragma unroll
            for (int j = 0; j < 8; j++) s[j] += a * hv[j];
        }
        float ic = inv_cs[v];
        uint4 xr = *(const uint4*)(x + (size_t)g * 64 + l8 * 8);
        float xv[8];
        unpack8(xr, xv);
#pragma unroll
        for (int j = 0; j < 8; j++) o[j] = 0.05f * xv[j] + 0.95f * (ic * s[j]);
        *(uint4*)(out2 + xoffs + (size_t)g * 64 + l8 * 8) = pack8(o);
    }
}

// mix projection via bf16 MFMA, both xp halves: block = (b,n); grid = dim3(CB*1024, 2)
__global__ __launch_bounds__(256) void k_proj(const unsigned short* xs,
        const unsigned short* h1, const unsigned short* h2,
        const unsigned short* h1b, const unsigned short* h2b,
        const unsigned short* mwp, const float* m1b, const float* m2b,
        unsigned short* mix, size_t xstride) {
    __shared__ unsigned short Bf[24 * 64 * 8];   // 24 shared B-frags, frag layout, 24 KB
    int xp = blockIdx.y;
    size_t xoffs = (size_t)xp * xstride;
    xs += xoffs; h1 += xoffs; h2 += xoffs; h1b += xoffs; h2b += xoffs;
    int t = threadIdx.x;
    int wave = t >> 6, l = t & 63;
    int lr = l & 15, lg = l >> 4;
    int b = blockIdx.x >> 10, n = blockIdx.x & 1023;
    // ---- cooperative B-frag gather: 6 frags per wave ----
#pragma unroll
    for (int i = 0; i < 6; i++) {
        int f = wave * 6 + i;
        int kb = f >> 2, nt = f & 3;
        int ph = (kb >= 3) ? 1 : 0;
        int q = kb - ph * 3;
        const unsigned short* Hq = (q == 0) ? xs : (q == 1 ? (ph ? h1b : h1)
                                                           : (ph ? h2b : h2));
        const unsigned short* src = Hq + ((size_t)(b * 32 + lg * 8) * 1024 + n) * 64
                                       + nt * 16 + lr;
        bf16x8 v;
#pragma unroll
        for (int j = 0; j < 8; j++)
            v[j] = (short)src[(size_t)j * 65536];
        *(bf16x8*)(Bf + ((size_t)f * 64 + l) * 8) = v;
    }
    __syncthreads();
    // ---- wave = row-tile; 4 col-tiles; K = 6 blocks of 32 ----
    f32x4 acc[4];
#pragma unroll
    for (int nt = 0; nt < 4; nt++) {
        f32x4 c;
#pragma unroll
        for (int r = 0; r < 4; r++) {
            int row = wave * 16 + lg * 4 + r;
            c[r] = m1b[row] + m2b[row];
        }
        acc[nt] = c;
    }
#pragma unroll
    for (int kb = 0; kb < 6; kb++) {
        bf16x8 af = *(const bf16x8*)(mwp + (size_t)((kb * 4 + wave) * 64 + l) * 8);
#pragma unroll
        for (int nt = 0; nt < 4; nt++) {
            bf16x8 bfv = *(const bf16x8*)(Bf + ((size_t)(kb * 4 + nt) * 64 + l) * 8);
            acc[nt] = __builtin_amdgcn_mfma_f32_16x16x32_bf16(af, bfv, acc[nt], 0, 0, 0);
        }
    }
#pragma unroll
    for (int nt = 0; nt < 4; nt++)
#pragma unroll
        for (int r = 0; r < 4; r++) {
            int row = wave * 16 + lg * 4 + r;
            int i2 = row >> 5, o = row & 31;
            mix[(size_t)((b * 32 + o) * 1024 + n) * 256 + (i2 * 2 + xp) * 64 + nt * 16 + lr]
                = f2bf(acc[nt][r]);
        }
}

// fused Wtf1(relu)Wtf2 via bf16 MFMA, in-place on bf16 mix: 32 rows/block; grid = CB*1024
__global__ __launch_bounds__(256) void k_tf(unsigned short* mix, const unsigned short* W1p,
                                            const float* B1, const unsigned short* W2p,
                                            const float* B2) {
    __shared__ unsigned short Abuf[32 * 256];   // bf16, XOR-swizzled
    __shared__ unsigned short Hbuf[32 * 256];
    int t = threadIdx.x;
    int wave = t >> 6, l = t & 63;
    size_t row0 = (size_t)blockIdx.x * 32;
    const uint4* src = (const uint4*)(mix + row0 * 256);
#pragma unroll
    for (int it = 0; it < 4; it++) {
        int f = t + it * 256;                  // 1024 8-u16 chunks
        uint4 raw = src[f];
        int e = f * 8, row = e >> 8, col = e & 255;
        int byte = (row * 512 + col * 2) ^ ((row & 7) << 4);
        *(uint4*)((char*)Abuf + byte) = raw;
    }
    __syncthreads();
    int colg0 = wave * 64;
    int lr = l & 15, lg = l >> 4;
    f32x4 acc[2][4];
#pragma unroll
    for (int nb = 0; nb < 4; nb++) {
        float bv = B1[colg0 + nb * 16 + lr];
        f32x4 c; c[0] = bv; c[1] = bv; c[2] = bv; c[3] = bv;
        acc[0][nb] = c; acc[1][nb] = c;
    }
#pragma unroll
    for (int kb = 0; kb < 8; kb++) {
        int k2 = (kb * 32 + lg * 8) * 2;
        int by0 = (lr * 512 + k2) ^ ((lr & 7) << 4);
        int by1 = ((16 + lr) * 512 + k2) ^ ((lr & 7) << 4);
        bf16x8 a0 = *(const bf16x8*)((char*)Abuf + by0);
        bf16x8 a1 = *(const bf16x8*)((char*)Abuf + by1);
#pragma unroll
        for (int nb = 0; nb < 4; nb++) {
            int nbg = wave * 4 + nb;
            bf16x8 bw = *(const bf16x8*)(W1p + (size_t)((kb * 16 + nbg) * 64 + l) * 8);
            acc[0][nb] = __builtin_amdgcn_mfma_f32_16x16x32_bf16(a0, bw, acc[0][nb], 0, 0, 0);
            acc[1][nb] = __builtin_amdgcn_mfma_f32_16x16x32_bf16(a1, bw, acc[1][nb], 0, 0, 0);
        }
    }
#pragma unroll
    for (int rb = 0; rb < 2; rb++)
#pragma unroll
        for (int nb = 0; nb < 4; nb++)
#pragma unroll
            for (int r = 0; r < 4; r++) {
                int row = rb * 16 + lg * 4 + r;
                int col = colg0 + nb * 16 + lr;
                unsigned short h = f2bf(fmaxf(acc[rb][nb][r], 0.f));
                int byte = (row * 512 + col * 2) ^ ((row & 7) << 4);
                *(unsigned short*)((char*)Hbuf + byte) = h;
            }
    __syncthreads();
#pragma unroll
    for (int nb = 0; nb < 4; nb++) {
        float bv = B2[colg0 + nb * 16 + lr];
        f32x4 c; c[0] = bv; c[1] = bv; c[2] = bv; c[3] = bv;
        acc[0][nb] = c; acc[1][nb] = c;
    }
#pragma unroll
    for (int kb = 0; kb < 8; kb++) {
        int k2 = (kb * 32 + lg * 8) * 2;
        int by0 = (lr * 512 + k2) ^ ((lr & 7) << 4);
        int by1 = ((16 + lr) * 512 + k2) ^ ((lr & 7) << 4);
        bf16x8 a0 = *(const bf16x8*)((char*)Hbuf + by0);
        bf16x8 a1 = *(const bf16x8*)((char*)Hbuf + by1);
#pragma unroll
        for (int nb = 0; nb < 4; nb++) {
            int nbg = wave * 4 + nb;
            bf16x8 bw = *(const bf16x8*)(W2p + (size_t)((kb * 16 + nbg) * 64 + l) * 8);
            acc[0][nb] = __builtin_amdgcn_mfma_f32_16x16x32_bf16(a0, bw, acc[0][nb], 0, 0, 0);
            acc[1][nb] = __builtin_amdgcn_mfma_f32_16x16x32_bf16(a1, bw, acc[1][nb], 0, 0, 0);
        }
    }
#pragma unroll
    for (int rb = 0; rb < 2; rb++)
#pragma unroll
        for (int nb = 0; nb < 4; nb++)
#pragma unroll
            for (int r = 0; r < 4; r++) {
                int row = rb * 16 + lg * 4 + r;
                int col = colg0 + nb * 16 + lr;
                mix[(row0 + row) * 256 + col] = f2bf(acc[rb][nb][r]);
            }
}

// fused ec1(relu)+ec2 via bf16 MFMA; bf16 mix in, bf16 eco out; grid = CB*1024
__global__ __launch_bounds__(256) void k_ec(const unsigned short* tfo,
        const unsigned short* W1p, const float* B1,
        const unsigned short* W2p, const float* B2, unsigned short* eco) {
    __shared__ unsigned short Hl[4 * 64 * 48];   // per-wave [64 l][48 u16] = 24 KB
    int t = threadIdx.x;
    int wave = t >> 6, l = t & 63;
    int lr = l & 15, lg = l >> 4;
    int b = blockIdx.x >> 10, n = blockIdx.x & 1023;
    int lbase = wave * 64;
    unsigned short* myH = Hl + wave * 3072;
    const unsigned short* xb = tfo + ((size_t)(b * 32) * 1024 + n) * 256;
    bf16x8 xf[4];
#pragma unroll
    for (int nt = 0; nt < 4; nt++) {
        int ll = lbase + nt * 16 + lr;
        bf16x8 v;
#pragma unroll
        for (int j = 0; j < 8; j++)
            v[j] = (short)xb[(size_t)(lg * 8 + j) * 262144 + ll];
        xf[nt] = v;
    }
    f32x4 d2[4];
    {
        f32x4 c;
#pragma unroll
        for (int r = 0; r < 4; r++) {
            int p = lg * 4 + r;
            c[r] = (p < 12) ? B2[p] : 0.f;
        }
#pragma unroll
        for (int nt = 0; nt < 4; nt++) d2[nt] = c;
    }
#pragma unroll
    for (int ch = 0; ch < 4; ch++) {
        f32x4 h[2][4];
#pragma unroll
        for (int mt = 0; mt < 2; mt++) {
            f32x4 c;
#pragma unroll
            for (int r = 0; r < 4; r++) c[r] = B1[ch * 32 + mt * 16 + lg * 4 + r];
#pragma unroll
            for (int nt = 0; nt < 4; nt++) h[mt][nt] = c;
        }
#pragma unroll
        for (int mt = 0; mt < 2; mt++) {
            bf16x8 aw = *(const bf16x8*)(W1p + (size_t)((ch * 2 + mt) * 64 + l) * 8);
#pragma unroll
            for (int nt = 0; nt < 4; nt++)
                h[mt][nt] = __builtin_amdgcn_mfma_f32_16x16x32_bf16(aw, xf[nt], h[mt][nt], 0, 0, 0);
        }
#pragma unroll
        for (int mt = 0; mt < 2; mt++)
#pragma unroll
            for (int nt = 0; nt < 4; nt++) {
                unsigned lo = f2bf(fmaxf(h[mt][nt][0], 0.f)) |
                              ((unsigned)f2bf(fmaxf(h[mt][nt][1], 0.f)) << 16);
                unsigned hi = f2bf(fmaxf(h[mt][nt][2], 0.f)) |
                              ((unsigned)f2bf(fmaxf(h[mt][nt][3], 0.f)) << 16);
                uint2 pk; pk.x = lo; pk.y = hi;
                *(uint2*)(myH + (nt * 16 + lr) * 48 + mt * 16 + lg * 4) = pk;
            }
        bf16x8 aw2 = *(const bf16x8*)(W2p + (size_t)(ch * 64 + l) * 8);
#pragma unroll
        for (int nt = 0; nt < 4; nt++) {
            bf16x8 hf = *(const bf16x8*)(myH + (nt * 16 + lr) * 48 + lg * 8);
            d2[nt] = __builtin_amdgcn_mfma_f32_16x16x32_bf16(aw2, hf, d2[nt], 0, 0, 0);
        }
    }
#pragma unroll
    for (int nt = 0; nt < 4; nt++)
#pragma unroll
        for (int r = 0; r < 4; r++) {
            int p = lg * 4 + r;
            if (p < 12) {
                int ll = lbase + nt * 16 + lr;
                eco[((size_t)(b * 12 + p) * 1024 + n) * 256 + ll] = f2bf(d2[nt][r]);
            }
        }
}

// stage relu(fh) into MFMA A-frag order: apk[(rg*15+kb)*64+lane][8]
// streaming, fully-coalesced writes; grid = CB*2880
__global__ __launch_bounds__(256) void k_stage(const unsigned short* gated,
        const unsigned short* eco, const unsigned short* hd_emb,
        const float* hist, const float* tide, const float* diwe,
        unsigned short* apk) {
    int id = blockIdx.x * 256 + threadIdx.x;
    int lane = id & 63, rest = id >> 6;
    int rg = rest / 15, kb = rest - rg * 15;    // kb wave-uniform
    int lr = lane & 15, lg = lane >> 4;
    int grow = rg * 16 + lr;
    int n = grow & 1023, bt = grow >> 10;
    int b = bt / 12, tt = bt - b * 12;
    int off = kb * 32 + lg * 8;
    bf16x8 v;
    if (kb <= 3) {
        v = relu8(*(const bf16x8*)(gated + (size_t)grow * 128 + off));
    } else if (kb <= 11) {
        v = relu8(*(const bf16x8*)(eco + (size_t)((b * 12 + tt) * 1024 + n) * 256 + off - 128));
    } else if (kb == 12) {
        int tid_i = (int)(hist[(size_t)grow * 4 + 2] * 288.0f);
        int diw_i = (int)hist[(size_t)grow * 4 + 3];
        const unsigned short* hptr = hd_emb + (size_t)grow * 64;
#pragma unroll
        for (int j = 0; j < 8; j++) {
            int k = off + j;                    // in [384, 416)
            float x;
            if (k < 396) x = tide[tid_i * 12 + k - 384];
            else if (k < 408) x = diwe[diw_i * 12 + k - 396];
            else x = bf2f(hptr[k - 408]);
            v[j] = (short)f2bf(fmaxf(x, 0.f));
        }
    } else if (kb == 13) {
        v = relu8(*(const bf16x8*)(hd_emb + (size_t)grow * 64 + off - 408));
    } else {                                    // kb == 14
        if (lg < 3) v = relu8(*(const bf16x8*)(hd_emb + (size_t)grow * 64 + off - 408));
        else {
#pragma unroll
            for (int j = 0; j < 8; j++) v[j] = 0;
        }
    }
    *(bf16x8*)(apk + (size_t)id * 8) = v;
}

// fc1(bf16 MFMA)+relu+fc2: ALL loads contiguous (A pre-packed by k_stage).
// 32 rows/block (two 16-row A-groups share every weight fetch), 4 waves x 128 cols;
// wave partials to pbuf; grid = CB*384
__global__ __launch_bounds__(256) void k_fc(const unsigned short* apk,
        const unsigned short* W1p, const float* B1, const float* W2,
        float* pbuf) {
    int t = threadIdx.x;
    int wave = t >> 6, l = t & 63;
    int lr = l & 15, lg = l >> 4;
    int rg0 = blockIdx.x * 2;
    int colg0 = wave * 128;
    f32x4 acc[2][8];
#pragma unroll
    for (int nb = 0; nb < 8; nb++) {
        float bv = B1[colg0 + nb * 16 + lr];
        f32x4 c; c[0] = bv; c[1] = bv; c[2] = bv; c[3] = bv;
        acc[0][nb] = c; acc[1][nb] = c;
    }
#pragma unroll
    for (int kb = 0; kb < 15; kb++) {
        bf16x8 af0 = *(const bf16x8*)(apk + (size_t)((rg0 * 15 + kb) * 64 + l) * 8);
        bf16x8 af1 = *(const bf16x8*)(apk + (size_t)(((rg0 + 1) * 15 + kb) * 64 + l) * 8);
#pragma unroll
        for (int nb = 0; nb < 8; nb++) {
            bf16x8 bw = *(const bf16x8*)(W1p + (size_t)((kb * 32 + wave * 8 + nb) * 64 + l) * 8);
            acc[0][nb] = __builtin_amdgcn_mfma_f32_16x16x32_bf16(af0, bw, acc[0][nb], 0, 0, 0);
            acc[1][nb] = __builtin_amdgcn_mfma_f32_16x16x32_bf16(af1, bw, acc[1][nb], 0, 0, 0);
        }
    }
    // ---- fc2: relu(acc) in fp32, in-register partials over this wave's 128 cols ----
    float p[2][4][3];
#pragma unroll
    for (int rr = 0; rr < 2; rr++)
#pragma unroll
        for (int r = 0; r < 4; r++) { p[rr][r][0] = 0.f; p[rr][r][1] = 0.f; p[rr][r][2] = 0.f; }
#pragma unroll
    for (int nb = 0; nb < 8; nb++) {
        int col = colg0 + nb * 16 + lr;
        float w0 = W2[col * 3], w1 = W2[col * 3 + 1], w2 = W2[col * 3 + 2];
#pragma unroll
        for (int rr = 0; rr < 2; rr++)
#pragma unroll
            for (int r = 0; r < 4; r++) {
                float h = fmaxf(acc[rr][nb][r], 0.f);
                p[rr][r][0] += h * w0; p[rr][r][1] += h * w1; p[rr][r][2] += h * w2;
            }
    }
#pragma unroll
    for (int off = 8; off >= 1; off >>= 1)
#pragma unroll
        for (int rr = 0; rr < 2; rr++)
#pragma unroll
            for (int r = 0; r < 4; r++) {
                p[rr][r][0] += __shfl_xor(p[rr][r][0], off);
                p[rr][r][1] += __shfl_xor(p[rr][r][1], off);
                p[rr][r][2] += __shfl_xor(p[rr][r][2], off);
            }
    if (lr == 0) {
#pragma unroll
        for (int rr = 0; rr < 2; rr++)
#pragma unroll
            for (int r = 0; r < 4; r++) {
                size_t gr = (size_t)((rg0 + rr) * 16 + lg * 4 + r);
#pragma unroll
                for (int pp = 0; pp < 3; pp++)
                    pbuf[gr * 12 + wave * 3 + pp] = p[rr][r][pp];
            }
    }
}

// final: sum 4 wave-partials + fc2 bias, conv1x1 over time, transpose; grid = CB*48
__global__ void k_ec3(const float* pbuf, const float* B2, const float* W, const float* bv,
                      float* out) {
    int idx = blockIdx.x * 256 + threadIdx.x;
    int l = idx % 3;
    int rest = idx / 3;
    int o = rest & 3;
    int n = (rest >> 2) & 1023;
    int b = rest >> 12;
    float s = bv[o];
#pragma unroll
    for (int c = 0; c < 12; c++) {
        const float* pb = pbuf + ((size_t)(b * 12 + c) * 1024 + n) * 12;
        float fv = B2[l] + pb[l] + pb[3 + l] + pb[6 + l] + pb[9 + l];
        s += fv * W[o * 12 + c];
    }
    out[idx] = s;
}

// ---------------- launcher ----------------
extern "C" void kernel_launch(void* const* d_in, const int* in_sizes, int n_in,
                              void* d_out, int out_size, void* d_ws, size_t ws_size,
                              hipStream_t stream) {
    const float* hist = (const float*)d_in[0];
    const float* node_emb_u = (const float*)d_in[1];
    const float* T_i_D_emb = (const float*)d_in[2];
    const float* D_i_W_emb = (const float*)d_in[3];
    const float* gc_emb1 = (const float*)d_in[4];
    const float* gc_emb2 = (const float*)d_in[5];
    const float* gc_w1 = (const float*)d_in[6];
    const float* gc_b1 = (const float*)d_in[7];
    const float* gc_w2 = (const float*)d_in[8];
    const float* gc_b2 = (const float*)d_in[9];
    const float* W_emb = (const float*)d_in[10];
    const float* b_emb = (const float*)d_in[11];
    const float* Wg1 = (const float*)d_in[12];
    const float* bg1 = (const float*)d_in[13];
    const float* Wg2 = (const float*)d_in[14];
    const float* bg2 = (const float*)d_in[15];
    const float* Wsc = (const float*)d_in[16];
    const float* bsc = (const float*)d_in[17];
    const float* mix1_w = (const float*)d_in[18];
    const float* mix1_b = (const float*)d_in[19];
    const float* mix2_w = (const float*)d_in[20];
    const float* mix2_b = (const float*)d_in[21];
    const float* Wtf1 = (const float*)d_in[22];
    const float* btf1 = (const float*)d_in[23];
    const float* Wtf2 = (const float*)d_in[24];
    const float* btf2 = (const float*)d_in[25];
    const float* Wec1 = (const float*)d_in[26];
    const float* bec1 = (const float*)d_in[27];
    const float* Wec2 = (const float*)d_in[28];
    const float* bec2 = (const float*)d_in[29];
    const float* Wfc1 = (const float*)d_in[30];
    const float* bfc1 = (const float*)d_in[31];
    const float* Wfc2 = (const float*)d_in[32];
    const float* bfc2 = (const float*)d_in[33];
    const float* Wec3 = (const float*)d_in[34];
    const float* bec3 = (const float*)d_in[35];

    float* ws = (float*)d_ws;
    float* n1 = ws + F_N1;
    float* n2 = ws + F_N2;
    float* aN_val = ws + F_ANVAL;
    float* row_val = ws + F_ROWVAL;
    float* col_sum = ws + F_COLSUM;
    float* inv_cs = ws + F_INVCS;
    float* aT_val = ws + F_ATVAL;
    int* aN_idx = (int*)(ws + I_ANIDX);
    int* row_idx = (int*)(ws + I_ROWIDX);
    int* col_cnt = (int*)(ws + I_COLCNT);
    int* col_off = (int*)(ws + I_COLOFF);
    int* col_fill = (int*)(ws + I_COLFILL);
    int* aT_idx = (int*)(ws + I_ATIDX);
    unsigned short* w1p = (unsigned short*)(ws + F_W1P);
    unsigned short* w2p = (unsigned short*)(ws + F_W2P);
    unsigned short* wfcp = (unsigned short*)(ws + F_WFCP);
    unsigned short* wec1p = (unsigned short*)(ws + F_WEC1P);
    unsigned short* wec2p = (unsigned short*)(ws + F_WEC2P);
    unsigned short* wmwp = (unsigned short*)(ws + F_WMWP);

    // pick largest batch-chunk CB that fits the workspace
    size_t avail = ws_size / 4;   // floats
    int CB = 8;
    while (CB > 1 && GRAPH_FLOATS + (size_t)CB * PB_TOTAL > avail) CB >>= 1;
    int nchunk = 8 / CB;

    size_t xstride = (size_t)CB * PB_X * 2;     // u16 per xp slab
    unsigned short* gated = (unsigned short*)(ws + GRAPH_FLOATS);
    unsigned short* hd_emb = (unsigned short*)(ws + GRAPH_FLOATS + (size_t)CB * PB_GATED);
    unsigned short* xs = (unsigned short*)(ws + GRAPH_FLOATS + (size_t)CB * (PB_GATED + PB_HD));
    unsigned short* h1 = xs + 2 * xstride;
    unsigned short* h2 = h1 + 2 * xstride;
    unsigned short* h1b = h2 + 2 * xstride;
    unsigned short* h2b = h1b + 2 * xstride;
    unsigned short* mix = h2b + 2 * xstride;
    unsigned short* apk = mix;       // alias: mix dead after k_ec; apk < mix size
    unsigned short* eco = xs;        // alias: xs(2 slabs = CB*4M u16) >= eco (CB*3M u16)
    float* fbuf = (float*)h2b;       // alias: h2b dead by k_fc (CB*147456 f32 partials)

    // ---- graph construction + weight packing (once) ----
    k_init<<<4, 256, 0, stream>>>(col_cnt, col_fill, col_sum);
    k_embed<<<320, 256, 0, stream>>>(gc_emb1, gc_emb2, gc_w1, gc_b1, gc_w2, gc_b2, n1, n2);
    k_adj<<<1024, 256, 0, stream>>>(n1, n2, aN_val, aN_idx, row_val, row_idx, col_cnt, col_sum);
    k_scan<<<1, 1024, 0, stream>>>(col_cnt, col_off, col_sum, inv_cs);
    k_scatter<<<40, 256, 0, stream>>>(row_idx, row_val, col_off, col_fill, aT_idx, aT_val);
    k_packw<<<32, 256, 0, stream>>>(Wtf1, w1p);
    k_packw<<<32, 256, 0, stream>>>(Wtf2, w2p);
    k_packfc<<<120, 256, 0, stream>>>(Wfc1, wfcp);
    k_packec<<<3, 256, 0, stream>>>(Wec1, Wec2, wec1p, wec2p);
    k_packmw<<<6, 256, 0, stream>>>(mix1_w, mix2_w, wmwp);

    // ---- per-chunk pipeline ----
    for (int ch = 0; ch < nchunk; ch++) {
        const float* hist_c = hist + (size_t)ch * CB * ROWS_PER_B * 4;
        float* out_c = (float*)d_out + (size_t)ch * CB * ROWS_PER_B;

        k_gate<<<CB * 768, 256, 0, stream>>>(hist_c, node_emb_u, T_i_D_emb, D_i_W_emb,
                                             Wg1, bg1, Wg2, bg2, W_emb, b_emb, gated, hd_emb);
        k_wsc<<<dim3(CB * 256, 2), 256, 0, stream>>>(gated, Wsc, bsc, xs, xstride);
        k_spmm2<<<dim3(CB * 1024, 4), 256, 0, stream>>>(h1, h1b, xs, xs, xs,
                                                        aN_idx, aN_val, aT_idx, aT_val,
                                                        col_off, inv_cs, xstride);
        k_spmm2<<<dim3(CB * 1024, 4), 256, 0, stream>>>(h2, h2b, xs, h1, h1b,
                                                        aN_idx, aN_val, aT_idx, aT_val,
                                                        col_off, inv_cs, xstride);
        k_proj<<<dim3(CB * 1024, 2), 256, 0, stream>>>(xs, h1, h2, h1b, h2b,
                                                       wmwp, mix1_b, mix2_b, mix, xstride);
        k_tf<<<CB * 1024, 256, 0, stream>>>(mix, w1p, btf1, w2p, btf2);
        k_ec<<<CB * 1024, 256, 0, stream>>>(mix, wec1p, bec1, wec2p, bec2, eco);
        k_stage<<<CB * 2880, 256, 0, stream>>>(gated, eco, hd_emb, hist_c,
                                               T_i_D_emb, D_i_W_emb, apk);
        k_fc<<<CB * 384, 256, 0, stream>>>(apk, wfcp, bfc1, Wfc2, fbuf);
        k_ec3<<<CB * 48, 256, 0, stream>>>(fbuf, bfc2, Wec3, bec3, out_c);
    }
}